// Round 1
// baseline (720.715 us; speedup 1.0000x reference)
//
#include <hip/hip_runtime.h>
#include <cstdint>
#include <cstddef>

#define D_IN   128
#define D_HID  32
#define D_OUT  32
#define NEG_SLOPE 0.2f
#define EPS_F  1e-16f

// ---------------------------------------------------------------------------
// edge_index may arrive as int32 or int64 (reference declares int64; harness
// note says int). Detect on device: values < 2^17, so int64 => every odd
// int32 word (high half, little-endian) of the first 64 pairs is zero.
// ---------------------------------------------------------------------------
__global__ void detect_kernel(const int* __restrict__ ei, long long E, int* __restrict__ flag) {
    if (blockIdx.x == 0 && threadIdx.x == 0) {
        long long n = E < 64 ? E : 64;
        int is64 = 1;
        for (long long k = 0; k < n; ++k) {
            if (ei[2 * k + 1] != 0) { is64 = 0; break; }
        }
        *flag = is64;
    }
}

__device__ __forceinline__ int edge_val(const int* __restrict__ ei, long long idx, int is64) {
    return is64 ? ei[idx * 2] : ei[idx];
}

// count degrees (incl. self-loops) by destination
__global__ void count_kernel(const int* __restrict__ ei, const int* __restrict__ flag,
                             long long E, long long E2, int* __restrict__ cnt) {
    const int is64 = *flag;
    long long stride = (long long)gridDim.x * blockDim.x;
    for (long long e = (long long)blockIdx.x * blockDim.x + threadIdx.x; e < E2; e += stride) {
        int d = (e < E) ? edge_val(ei, E + e, is64) : (int)(e - E);
        atomicAdd(&cnt[d], 1);
    }
}

// single-block exclusive scan over cnt[N] -> rowptr[N+1], cursor copy, dis = 1/sqrt(deg)
__global__ void scan_kernel(const int* __restrict__ cnt, int* __restrict__ rowptr,
                            int* __restrict__ cursor, float* __restrict__ dis, int N) {
    __shared__ int swsum[16];
    __shared__ int swoff[16];
    const int t = threadIdx.x;              // 1024 threads
    const int chunk = (N + 1023) >> 10;
    const int lo = t * chunk;
    const int hi = min(N, lo + chunk);
    int s = 0;
    for (int i = lo; i < hi; ++i) s += cnt[i];
    const int lane = t & 63, wid = t >> 6;
    int incl = s;
    #pragma unroll
    for (int d = 1; d < 64; d <<= 1) {
        int v = __shfl_up(incl, d);
        if (lane >= d) incl += v;
    }
    if (lane == 63) swsum[wid] = incl;
    __syncthreads();
    if (t == 0) {
        int run = 0;
        for (int w = 0; w < 16; ++w) { swoff[w] = run; run += swsum[w]; }
    }
    __syncthreads();
    int run = incl - s + swoff[wid];        // exclusive prefix for this thread's chunk
    for (int i = lo; i < hi; ++i) {
        rowptr[i] = run;
        cursor[i] = run;
        int cv = cnt[i];
        dis[i] = 1.0f / sqrtf((float)cv);   // deg >= 1 always (self-loop)
        run += cv;
    }
    if (t == 1023) rowptr[N] = run;         // last chunk empty or ends at N: run == total
}

// scatter src ids into CSR-by-dst order
__global__ void fill_kernel(const int* __restrict__ ei, const int* __restrict__ flag,
                            long long E, long long E2,
                            int* __restrict__ cursor, int* __restrict__ csr_src) {
    const int is64 = *flag;
    long long stride = (long long)gridDim.x * blockDim.x;
    for (long long e = (long long)blockIdx.x * blockDim.x + threadIdx.x; e < E2; e += stride) {
        int s, d;
        if (e < E) { s = edge_val(ei, e, is64); d = edge_val(ei, E + e, is64); }
        else       { s = d = (int)(e - E); }
        int pos = atomicAdd(&cursor[d], 1);
        csr_src[pos] = s;
    }
}

// hws[i][:] = dis[i] * (x[i] @ W1)      (pre-scaled so GCN gather needs no dis[src])
__global__ void gemm1_kernel(const float* __restrict__ x, const float* __restrict__ W1,
                             const float* __restrict__ dis, float* __restrict__ hws, int N) {
    __shared__ float sW[D_IN * D_HID];      // 16 KB
    __shared__ float sx[8][D_IN];           // 4 KB
    const int t = threadIdx.x;              // 256
    const int c = t & 31, r = t >> 5;
    for (int i = t; i < D_IN * D_HID; i += 256) sW[i] = W1[i];
    for (long long base = (long long)blockIdx.x * 8; base < N; base += (long long)gridDim.x * 8) {
        __syncthreads();
        // stage 8 rows (1024 floats) with float4 loads: 256 threads x 16B
        if (base + 8 <= N) {
            const float4* xp = (const float4*)(x + base * D_IN);
            float4 v = xp[t];
            sx[t >> 5][(t & 31) * 4 + 0] = v.x;
            sx[t >> 5][(t & 31) * 4 + 1] = v.y;
            sx[t >> 5][(t & 31) * 4 + 2] = v.z;
            sx[t >> 5][(t & 31) * 4 + 3] = v.w;
        } else {
            long long nrem = (N - base) * D_IN;
            for (int i = t; i < nrem; i += 256) sx[i >> 7][i & 127] = x[base * D_IN + i];
        }
        __syncthreads();
        long long row = base + r;
        if (row < N) {
            float acc = 0.0f;
            #pragma unroll 16
            for (int k = 0; k < D_IN; ++k) acc = fmaf(sx[r][k], sW[k * D_HID + c], acc);
            hws[row * D_HID + c] = acc * dis[row];
        }
    }
}

// GCN aggregate + bias + ReLU: h1[i] = relu(dis[i] * sum_{s in nbr(i)} hws[s] + b1)
__global__ void gcn_agg_kernel(const int* __restrict__ rowptr, const int* __restrict__ csr_src,
                               const float* __restrict__ hws, const float* __restrict__ dis,
                               const float* __restrict__ b1, float* __restrict__ h1, int N) {
    const int lane = threadIdx.x & 63;
    const int c = lane & 31, half = lane >> 5;
    const int wib = threadIdx.x >> 6;       // 4 waves / block
    for (int i = blockIdx.x * 4 + wib; i < N; i += gridDim.x * 4) {
        const int b = rowptr[i], e = rowptr[i + 1];
        float acc = 0.0f;
        for (int j = b + half; j < e; j += 2) {
            int s = csr_src[j];
            acc += hws[(long long)s * D_HID + c];
        }
        acc += __shfl_xor(acc, 32);
        if (half == 0) {
            float v = dis[i] * acc + b1[c];
            h1[(long long)i * D_HID + c] = v > 0.0f ? v : 0.0f;
        }
    }
}

// g = h1 @ W2 ; a_s = g @ att_src ; a_d = g @ att_dst
__global__ void gemm2_kernel(const float* __restrict__ h1, const float* __restrict__ W2,
                             const float* __restrict__ att_s, const float* __restrict__ att_d,
                             float* __restrict__ g, float* __restrict__ a_s, float* __restrict__ a_d,
                             int N) {
    __shared__ float sW[D_HID * D_OUT];     // 4 KB
    __shared__ float sas[D_OUT], sad[D_OUT];
    __shared__ float sh[8][D_HID];          // 1 KB
    const int t = threadIdx.x;              // 256
    const int c = t & 31, r = t >> 5;
    for (int i = t; i < D_HID * D_OUT; i += 256) sW[i] = W2[i];
    if (t < D_OUT) { sas[t] = att_s[t]; sad[t] = att_d[t]; }
    for (long long base = (long long)blockIdx.x * 8; base < N; base += (long long)gridDim.x * 8) {
        __syncthreads();
        if (base * D_HID + t < (long long)N * D_HID) sh[r][c] = h1[base * D_HID + t];
        __syncthreads();
        long long row = base + r;
        if (row < N) {
            float gv = 0.0f;
            #pragma unroll
            for (int k = 0; k < D_HID; ++k) gv = fmaf(sh[r][k], sW[k * D_OUT + c], gv);
            g[row * D_OUT + c] = gv;
            float ps = gv * sas[c];
            float pd = gv * sad[c];
            #pragma unroll
            for (int d = 16; d >= 1; d >>= 1) {
                ps += __shfl_xor(ps, d);
                pd += __shfl_xor(pd, d);
            }
            if (c == 0) { a_s[row] = ps; a_d[row] = pd; }
        }
    }
}

// GAT aggregate with online segment-softmax (wave per node, 2 edges in flight)
__global__ void gat_agg_kernel(const int* __restrict__ rowptr, const int* __restrict__ csr_src,
                               const float* __restrict__ g, const float* __restrict__ a_s,
                               const float* __restrict__ a_d, const float* __restrict__ b2,
                               float* __restrict__ out, int N) {
    const int lane = threadIdx.x & 63;
    const int c = lane & 31, half = lane >> 5;
    const int wib = threadIdx.x >> 6;
    for (int i = blockIdx.x * 4 + wib; i < N; i += gridDim.x * 4) {
        const int b = rowptr[i], e = rowptr[i + 1];
        const float adi = a_d[i];
        float m = -__builtin_inff(), ssum = 0.0f, acc = 0.0f;
        for (int j = b + half; j < e; j += 2) {
            int s = csr_src[j];
            float ev = a_s[s] + adi;
            ev = ev > 0.0f ? ev : NEG_SLOPE * ev;
            float mn = fmaxf(m, ev);
            float scale = __expf(m - mn);   // first iter: exp(-inf)=0, state is 0 anyway
            float w = __expf(ev - mn);
            ssum = ssum * scale + w;
            acc  = acc  * scale + w * g[(long long)s * D_OUT + c];
            m = mn;
        }
        // merge the two half-wave partials (half 0 is nonempty since deg>=1)
        float mo = __shfl_xor(m, 32);
        float so = __shfl_xor(ssum, 32);
        float ao = __shfl_xor(acc, 32);
        float M = fmaxf(m, mo);
        float e0 = __expf(m - M), e1 = __expf(mo - M);
        float S = ssum * e0 + so * e1;
        float A = acc  * e0 + ao * e1;
        if (half == 0) {
            out[(long long)i * D_OUT + c] = A / (S + EPS_F) + b2[c];
        }
    }
}

extern "C" void kernel_launch(void* const* d_in, const int* in_sizes, int n_in,
                              void* d_out, int out_size, void* d_ws, size_t ws_size,
                              hipStream_t stream) {
    const float* x       = (const float*)d_in[0];
    const int*   ei      = (const int*)d_in[1];   // int32 or int64, detected on device
    const float* W1      = (const float*)d_in[2];
    const float* b1      = (const float*)d_in[3];
    const float* W2      = (const float*)d_in[4];
    const float* att_src = (const float*)d_in[5];
    const float* att_dst = (const float*)d_in[6];
    const float* b2      = (const float*)d_in[7];
    float* out = (float*)d_out;

    const long long N  = in_sizes[0] / D_IN;
    const long long E  = in_sizes[1] / 2;
    const long long E2 = E + N;

    // workspace layout (256B aligned slices)
    char* ws = (char*)d_ws;
    size_t off = 0;
    auto alloc = [&](size_t bytes) -> void* {
        off = (off + 255) & ~(size_t)255;
        void* p = ws + off;
        off += bytes;
        return p;
    };
    int*   flag    = (int*)  alloc(16);
    int*   cnt     = (int*)  alloc((size_t)N * 4);
    int*   rowptr  = (int*)  alloc((size_t)(N + 1) * 4);
    int*   cursor  = (int*)  alloc((size_t)N * 4);
    int*   csr_src = (int*)  alloc((size_t)E2 * 4);
    float* dis     = (float*)alloc((size_t)N * 4);
    float* hws     = (float*)alloc((size_t)N * D_HID * 4);
    float* h1      = (float*)alloc((size_t)N * D_HID * 4);
    float* gbuf    = (float*)alloc((size_t)N * D_OUT * 4);
    float* as      = (float*)alloc((size_t)N * 4);
    float* ad      = (float*)alloc((size_t)N * 4);
    (void)ws_size; (void)n_in; (void)out_size;

    detect_kernel<<<1, 64, 0, stream>>>(ei, E, flag);
    hipMemsetAsync(cnt, 0, (size_t)N * 4, stream);
    count_kernel<<<2048, 256, 0, stream>>>(ei, flag, E, E2, cnt);
    scan_kernel<<<1, 1024, 0, stream>>>(cnt, rowptr, cursor, dis, (int)N);
    fill_kernel<<<2048, 256, 0, stream>>>(ei, flag, E, E2, cursor, csr_src);
    gemm1_kernel<<<1024, 256, 0, stream>>>(x, W1, dis, hws, (int)N);
    int agg_blocks = (int)((N + 3) / 4);
    gcn_agg_kernel<<<agg_blocks, 256, 0, stream>>>(rowptr, csr_src, hws, dis, b1, h1, (int)N);
    gemm2_kernel<<<1024, 256, 0, stream>>>(h1, W2, att_src, att_dst, gbuf, as, ad, (int)N);
    gat_agg_kernel<<<agg_blocks, 256, 0, stream>>>(rowptr, csr_src, gbuf, as, ad, b2, out, (int)N);
}

// Round 2
// 467.598 us; speedup vs baseline: 1.5413x; 1.5413x over previous
//
#include <hip/hip_runtime.h>
#include <cstdint>
#include <cstddef>

#define D_IN   128
#define D_HID  32
#define D_OUT  32
#define NEG_SLOPE 0.2f
#define EPS_F  1e-16f
#define SCAN_CHUNK 1024   // elements per block in phase A (256 thr x 4)

// ---------------------------------------------------------------------------
// edge_index may arrive as int32 or int64. Detect on device: values < 2^17,
// so int64 => every odd int32 word (high half, LE) of the first 64 pairs is 0.
// Parallel: one wave, one ballot.
// ---------------------------------------------------------------------------
__global__ void detect_kernel(const int* __restrict__ ei, long long E, int* __restrict__ flag) {
    const int t = threadIdx.x;                     // 64 threads
    long long n = E < 64 ? E : 64;
    int bad = (t < n && ei[2 * t + 1] != 0) ? 1 : 0;
    unsigned long long mask = __ballot(bad);
    if (t == 0) *flag = (mask == 0ULL) ? 1 : 0;
}

__device__ __forceinline__ int edge_val(const int* __restrict__ ei, long long idx, int is64) {
    return is64 ? ei[idx * 2] : ei[idx];
}

// count degrees (incl. self-loops) by destination
__global__ void count_kernel(const int* __restrict__ ei, const int* __restrict__ flag,
                             long long E, long long E2, int* __restrict__ cnt) {
    const int is64 = *flag;
    long long stride = (long long)gridDim.x * blockDim.x;
    for (long long e = (long long)blockIdx.x * blockDim.x + threadIdx.x; e < E2; e += stride) {
        int d = (e < E) ? edge_val(ei, E + e, is64) : (int)(e - E);
        atomicAdd(&cnt[d], 1);
    }
}

// ---------------- hierarchical scan: cnt[N] -> rowptr/cursor/dis ----------
// Phase A: per-block local exclusive scan (1024 elems/block), blocksum[b]=total
__global__ void scan_a_kernel(const int* __restrict__ cnt, int* __restrict__ rowptr,
                              float* __restrict__ dis, int* __restrict__ blocksum, int N) {
    __shared__ int wsum[4];                        // 256 threads = 4 waves
    const int t = threadIdx.x;
    const int base = blockIdx.x * SCAN_CHUNK;
    const int i0 = base + t * 4;
    int v[4];
    int s = 0;
    if (i0 + 4 <= N) {
        int4 c4 = *(const int4*)(cnt + i0);
        v[0] = c4.x; v[1] = c4.y; v[2] = c4.z; v[3] = c4.w;
        #pragma unroll
        for (int k = 0; k < 4; ++k) {
            s += v[k];
            dis[i0 + k] = rsqrtf((float)v[k]);     // deg >= 1 (self-loop)
        }
    } else {
        #pragma unroll
        for (int k = 0; k < 4; ++k) {
            int idx = i0 + k;
            int c = (idx < N) ? cnt[idx] : 0;
            v[k] = c; s += c;
            if (idx < N) dis[idx] = rsqrtf((float)c);
        }
    }
    const int lane = t & 63, wid = t >> 6;
    int incl = s;
    #pragma unroll
    for (int d = 1; d < 64; d <<= 1) {
        int u = __shfl_up(incl, d);
        if (lane >= d) incl += u;
    }
    if (lane == 63) wsum[wid] = incl;
    __syncthreads();
    int woff = 0;
    for (int w = 0; w < wid; ++w) woff += wsum[w];
    int excl = woff + incl - s;
    #pragma unroll
    for (int k = 0; k < 4; ++k) {
        int idx = i0 + k;
        if (idx < N) rowptr[idx] = excl;
        excl += v[k];
    }
    if (t == 255) blocksum[blockIdx.x] = woff + incl;
}

// Phase B: single block scans blocksum[NB] exclusive in-place; rowptr[N]=E2
__global__ void scan_b_kernel(int* __restrict__ blocksum, int* __restrict__ rowptr,
                              int NB, int N, int total) {
    __shared__ int wsum[16];
    __shared__ int carry_s;
    const int t = threadIdx.x;                     // 1024
    const int lane = t & 63, wid = t >> 6;
    if (t == 0) carry_s = 0;
    __syncthreads();
    for (int start = 0; start < NB; start += 1024) {
        int idx = start + t;
        int v = (idx < NB) ? blocksum[idx] : 0;
        int incl = v;
        #pragma unroll
        for (int d = 1; d < 64; d <<= 1) {
            int u = __shfl_up(incl, d);
            if (lane >= d) incl += u;
        }
        if (lane == 63) wsum[wid] = incl;
        __syncthreads();
        int woff = 0;
        for (int w = 0; w < wid; ++w) woff += wsum[w];
        int carry = carry_s;
        __syncthreads();
        if (idx < NB) blocksum[idx] = carry + woff + incl - v;
        if (t == 1023) carry_s = carry + woff + incl;
        __syncthreads();
    }
    if (t == 0) rowptr[N] = total;
}

// Phase C: add block offsets; cursor copy
__global__ void scan_c_kernel(int* __restrict__ rowptr, int* __restrict__ cursor,
                              const int* __restrict__ blocksum, int N) {
    int idx = blockIdx.x * blockDim.x + threadIdx.x;
    if (idx < N) {
        int r = rowptr[idx] + blocksum[idx / SCAN_CHUNK];
        rowptr[idx] = r;
        cursor[idx] = r;
    }
}

// scatter src ids into CSR-by-dst order
__global__ void fill_kernel(const int* __restrict__ ei, const int* __restrict__ flag,
                            long long E, long long E2,
                            int* __restrict__ cursor, int* __restrict__ csr_src) {
    const int is64 = *flag;
    long long stride = (long long)gridDim.x * blockDim.x;
    for (long long e = (long long)blockIdx.x * blockDim.x + threadIdx.x; e < E2; e += stride) {
        int s, d;
        if (e < E) { s = edge_val(ei, e, is64); d = edge_val(ei, E + e, is64); }
        else       { s = d = (int)(e - E); }
        int pos = atomicAdd(&cursor[d], 1);
        csr_src[pos] = s;
    }
}

// hws[i][:] = dis[i] * (x[i] @ W1)      (pre-scaled so GCN gather needs no dis[src])
__global__ void gemm1_kernel(const float* __restrict__ x, const float* __restrict__ W1,
                             const float* __restrict__ dis, float* __restrict__ hws, int N) {
    __shared__ float sW[D_IN * D_HID];      // 16 KB
    __shared__ float sx[8][D_IN];           // 4 KB
    const int t = threadIdx.x;              // 256
    const int c = t & 31, r = t >> 5;
    for (int i = t; i < D_IN * D_HID; i += 256) sW[i] = W1[i];
    for (long long base = (long long)blockIdx.x * 8; base < N; base += (long long)gridDim.x * 8) {
        __syncthreads();
        if (base + 8 <= N) {
            const float4* xp = (const float4*)(x + base * D_IN);
            float4 v = xp[t];
            sx[t >> 5][(t & 31) * 4 + 0] = v.x;
            sx[t >> 5][(t & 31) * 4 + 1] = v.y;
            sx[t >> 5][(t & 31) * 4 + 2] = v.z;
            sx[t >> 5][(t & 31) * 4 + 3] = v.w;
        } else {
            long long nrem = (N - base) * D_IN;
            for (int i = t; i < nrem; i += 256) sx[i >> 7][i & 127] = x[base * D_IN + i];
        }
        __syncthreads();
        long long row = base + r;
        if (row < N) {
            float acc = 0.0f;
            #pragma unroll 16
            for (int k = 0; k < D_IN; ++k) acc = fmaf(sx[r][k], sW[k * D_HID + c], acc);
            hws[row * D_HID + c] = acc * dis[row];
        }
    }
}

// GCN aggregate + bias + ReLU: h1[i] = relu(dis[i] * sum_{s in nbr(i)} hws[s] + b1)
__global__ void gcn_agg_kernel(const int* __restrict__ rowptr, const int* __restrict__ csr_src,
                               const float* __restrict__ hws, const float* __restrict__ dis,
                               const float* __restrict__ b1, float* __restrict__ h1, int N) {
    const int lane = threadIdx.x & 63;
    const int c = lane & 31, half = lane >> 5;
    const int wib = threadIdx.x >> 6;       // 4 waves / block
    for (int i = blockIdx.x * 4 + wib; i < N; i += gridDim.x * 4) {
        const int b = rowptr[i], e = rowptr[i + 1];
        float acc = 0.0f;
        for (int j = b + half; j < e; j += 2) {
            int s = csr_src[j];
            acc += hws[(long long)s * D_HID + c];
        }
        acc += __shfl_xor(acc, 32);
        if (half == 0) {
            float v = dis[i] * acc + b1[c];
            h1[(long long)i * D_HID + c] = v > 0.0f ? v : 0.0f;
        }
    }
}

// g = h1 @ W2 ; a_s = g @ att_src ; a_d = g @ att_dst
__global__ void gemm2_kernel(const float* __restrict__ h1, const float* __restrict__ W2,
                             const float* __restrict__ att_s, const float* __restrict__ att_d,
                             float* __restrict__ g, float* __restrict__ a_s, float* __restrict__ a_d,
                             int N) {
    __shared__ float sW[D_HID * D_OUT];     // 4 KB
    __shared__ float sas[D_OUT], sad[D_OUT];
    __shared__ float sh[8][D_HID];          // 1 KB
    const int t = threadIdx.x;              // 256
    const int c = t & 31, r = t >> 5;
    for (int i = t; i < D_HID * D_OUT; i += 256) sW[i] = W2[i];
    if (t < D_OUT) { sas[t] = att_s[t]; sad[t] = att_d[t]; }
    for (long long base = (long long)blockIdx.x * 8; base < N; base += (long long)gridDim.x * 8) {
        __syncthreads();
        if (base * D_HID + t < (long long)N * D_HID) sh[r][c] = h1[base * D_HID + t];
        __syncthreads();
        long long row = base + r;
        if (row < N) {
            float gv = 0.0f;
            #pragma unroll
            for (int k = 0; k < D_HID; ++k) gv = fmaf(sh[r][k], sW[k * D_OUT + c], gv);
            g[row * D_OUT + c] = gv;
            float ps = gv * sas[c];
            float pd = gv * sad[c];
            #pragma unroll
            for (int d = 16; d >= 1; d >>= 1) {
                ps += __shfl_xor(ps, d);
                pd += __shfl_xor(pd, d);
            }
            if (c == 0) { a_s[row] = ps; a_d[row] = pd; }
        }
    }
}

// GAT aggregate with online segment-softmax (wave per node, 2 edges in flight)
__global__ void gat_agg_kernel(const int* __restrict__ rowptr, const int* __restrict__ csr_src,
                               const float* __restrict__ g, const float* __restrict__ a_s,
                               const float* __restrict__ a_d, const float* __restrict__ b2,
                               float* __restrict__ out, int N) {
    const int lane = threadIdx.x & 63;
    const int c = lane & 31, half = lane >> 5;
    const int wib = threadIdx.x >> 6;
    for (int i = blockIdx.x * 4 + wib; i < N; i += gridDim.x * 4) {
        const int b = rowptr[i], e = rowptr[i + 1];
        const float adi = a_d[i];
        float m = -__builtin_inff(), ssum = 0.0f, acc = 0.0f;
        for (int j = b + half; j < e; j += 2) {
            int s = csr_src[j];
            float ev = a_s[s] + adi;
            ev = ev > 0.0f ? ev : NEG_SLOPE * ev;
            float mn = fmaxf(m, ev);
            float scale = __expf(m - mn);   // first iter: exp(-inf)=0, state is 0 anyway
            float w = __expf(ev - mn);
            ssum = ssum * scale + w;
            acc  = acc  * scale + w * g[(long long)s * D_OUT + c];
            m = mn;
        }
        float mo = __shfl_xor(m, 32);
        float so = __shfl_xor(ssum, 32);
        float ao = __shfl_xor(acc, 32);
        float M = fmaxf(m, mo);
        float e0 = __expf(m - M), e1 = __expf(mo - M);
        float S = ssum * e0 + so * e1;
        float A = acc  * e0 + ao * e1;
        if (half == 0) {
            out[(long long)i * D_OUT + c] = A / (S + EPS_F) + b2[c];
        }
    }
}

extern "C" void kernel_launch(void* const* d_in, const int* in_sizes, int n_in,
                              void* d_out, int out_size, void* d_ws, size_t ws_size,
                              hipStream_t stream) {
    const float* x       = (const float*)d_in[0];
    const int*   ei      = (const int*)d_in[1];   // int32 or int64, detected on device
    const float* W1      = (const float*)d_in[2];
    const float* b1      = (const float*)d_in[3];
    const float* W2      = (const float*)d_in[4];
    const float* att_src = (const float*)d_in[5];
    const float* att_dst = (const float*)d_in[6];
    const float* b2      = (const float*)d_in[7];
    float* out = (float*)d_out;

    const long long N  = in_sizes[0] / D_IN;
    const long long E  = in_sizes[1] / 2;
    const long long E2 = E + N;
    const int NB = (int)((N + SCAN_CHUNK - 1) / SCAN_CHUNK);

    // workspace layout (256B aligned slices)
    char* ws = (char*)d_ws;
    size_t off = 0;
    auto alloc = [&](size_t bytes) -> void* {
        off = (off + 255) & ~(size_t)255;
        void* p = ws + off;
        off += bytes;
        return p;
    };
    int*   flag     = (int*)  alloc(16);
    int*   cnt      = (int*)  alloc((size_t)N * 4);
    int*   rowptr   = (int*)  alloc((size_t)(N + 1) * 4);
    int*   cursor   = (int*)  alloc((size_t)N * 4);
    int*   csr_src  = (int*)  alloc((size_t)E2 * 4);
    float* dis      = (float*)alloc((size_t)N * 4);
    float* hws      = (float*)alloc((size_t)N * D_HID * 4);
    float* h1       = (float*)alloc((size_t)N * D_HID * 4);
    float* gbuf     = (float*)alloc((size_t)N * D_OUT * 4);
    float* as       = (float*)alloc((size_t)N * 4);
    float* ad       = (float*)alloc((size_t)N * 4);
    int*   blocksum = (int*)  alloc((size_t)NB * 4);
    (void)ws_size; (void)n_in; (void)out_size;

    detect_kernel<<<1, 64, 0, stream>>>(ei, E, flag);
    hipMemsetAsync(cnt, 0, (size_t)N * 4, stream);
    count_kernel<<<2048, 256, 0, stream>>>(ei, flag, E, E2, cnt);
    scan_a_kernel<<<NB, 256, 0, stream>>>(cnt, rowptr, dis, blocksum, (int)N);
    scan_b_kernel<<<1, 1024, 0, stream>>>(blocksum, rowptr, NB, (int)N, (int)E2);
    scan_c_kernel<<<(int)((N + 255) / 256), 256, 0, stream>>>(rowptr, cursor, blocksum, (int)N);
    fill_kernel<<<2048, 256, 0, stream>>>(ei, flag, E, E2, cursor, csr_src);
    gemm1_kernel<<<1024, 256, 0, stream>>>(x, W1, dis, hws, (int)N);
    int agg_blocks = (int)((N + 3) / 4);
    gcn_agg_kernel<<<agg_blocks, 256, 0, stream>>>(rowptr, csr_src, hws, dis, b1, h1, (int)N);
    gemm2_kernel<<<1024, 256, 0, stream>>>(h1, W2, att_src, att_dst, gbuf, as, ad, (int)N);
    gat_agg_kernel<<<agg_blocks, 256, 0, stream>>>(rowptr, csr_src, gbuf, as, ad, b2, out, (int)N);
}